// Round 7
// baseline (327.388 us; speedup 1.0000x reference)
//
#include <hip/hip_runtime.h>
#include <hip/hip_bf16.h>

// Problem constants: B=2, C=512, H=W=64 -> N=4096, G=32 (16 ch/group), EPS=1e-6.

typedef float f32x4 __attribute__((ext_vector_type(4)));
typedef __bf16 bf16x8 __attribute__((ext_vector_type(8)));

typedef const __attribute__((address_space(1))) unsigned char* gas_p;
typedef __attribute__((address_space(3))) unsigned char* las_p;

__device__ __forceinline__ void gload_lds16(const void* g, void* l) {
  // async DMA: each lane contributes 16B; LDS dst = wave-uniform base + lane*16
  __builtin_amdgcn_global_load_lds((gas_p)g, (las_p)l, 16, 0, 0);
}

// ====== prelude: weight cvt (4x1024 blocks) | gn_stats (64) | bcat (1) ======
__global__ __launch_bounds__(256) void prelude_k(
    const float* __restrict__ wq, const float* __restrict__ wk,
    const float* __restrict__ wv, const float* __restrict__ wo,
    __hip_bfloat16* __restrict__ wqkb, __hip_bfloat16* __restrict__ wvb,
    __hip_bfloat16* __restrict__ wob, const float* __restrict__ bq,
    const float* __restrict__ bk, float* __restrict__ bqk,
    const float* __restrict__ x, float* __restrict__ stats) {
  int bid = blockIdx.x;
  if (bid < 4096) {
    const float* src;
    __hip_bfloat16* dst;
    if (bid < 1024)      { src = wq; dst = wqkb; }
    else if (bid < 2048) { src = wk; dst = wqkb + 262144; }
    else if (bid < 3072) { src = wv; dst = wvb; }
    else                 { src = wo; dst = wob; }
    int i = (bid & 1023) * 256 + threadIdx.x;  // 1024*256 = 262144 = 512*512
    dst[i] = __float2bfloat16(src[i]);
    return;
  }
  if (bid < 4160) {  // gn_stats: one block per (b,g)
    int bg = bid - 4096;
    const float4* p = (const float4*)(x + (size_t)bg * 65536);
    float s = 0.f, s2 = 0.f;
    for (int i = threadIdx.x; i < 16384; i += 256) {
      float4 v = p[i];
      s  += v.x + v.y + v.z + v.w;
      s2 += v.x * v.x + v.y * v.y + v.z * v.z + v.w * v.w;
    }
#pragma unroll
    for (int off = 32; off > 0; off >>= 1) {
      s  += __shfl_xor(s, off);
      s2 += __shfl_xor(s2, off);
    }
    __shared__ float rs[4], rs2[4];
    int wid = threadIdx.x >> 6, lane = threadIdx.x & 63;
    if (lane == 0) { rs[wid] = s; rs2[wid] = s2; }
    __syncthreads();
    if (threadIdx.x == 0) {
      float S  = rs[0] + rs[1] + rs[2] + rs[3];
      float S2 = rs2[0] + rs2[1] + rs2[2] + rs2[3];
      float mean = S * (1.f / 65536.f);
      float var  = S2 * (1.f / 65536.f) - mean * mean;
      stats[bg * 2]     = mean;
      stats[bg * 2 + 1] = rsqrtf(var + 1e-6f);
    }
    return;
  }
  // bcat
  for (int j = threadIdx.x; j < 1024; j += 256)
    bqk[j] = (j < 512) ? bq[j] : bk[j - 512];
}

// ------- GroupNorm apply + transpose, vectorized: x fp32 -> hf bf16 [b][n][c]
__global__ __launch_bounds__(256) void gn_apply_k(const float* __restrict__ x,
                                                  const float* __restrict__ stats,
                                                  const float* __restrict__ gw,
                                                  const float* __restrict__ gb,
                                                  __hip_bfloat16* __restrict__ hf) {
  int c0 = blockIdx.x * 64, n0 = blockIdx.y * 64, b = blockIdx.z;
  __shared__ float tile[64][65];
  int tid = threadIdx.x;
  int cl = tid >> 2, q = tid & 3;
  int c = c0 + cl;
  float mean = stats[(b * 32 + (c >> 4)) * 2];
  float rstd = stats[(b * 32 + (c >> 4)) * 2 + 1];
  float sc = rstd * gw[c];
  float sh = gb[c] - mean * sc;
  const float* xr = x + ((size_t)(b * 512 + c0 + cl)) * 4096 + n0 + q * 16;
#pragma unroll
  for (int j = 0; j < 4; j++) {
    float4 v = *(const float4*)(xr + 4 * j);
    int n = q * 16 + 4 * j;
    tile[cl][n]     = v.x * sc + sh;
    tile[cl][n + 1] = v.y * sc + sh;
    tile[cl][n + 2] = v.z * sc + sh;
    tile[cl][n + 3] = v.w * sc + sh;
  }
  __syncthreads();
  int nl = tid >> 2, ch = q * 16;
  bf16x8 o0, o1;
#pragma unroll
  for (int l = 0; l < 8; l++) {
    o0[l] = (__bf16)tile[ch + l][nl];
    o1[l] = (__bf16)tile[ch + 8 + l][nl];
  }
  __hip_bfloat16* op = hf + ((size_t)(b * 4096 + n0 + nl)) * 512 + c0 + ch;
  *(uint4*)op = *(uint4*)&o0;
  *(uint4*)(op + 8) = *(uint4*)&o1;
}

// ============ fused QKV (double-buffered DMA + LDS epilogue) ============
// bx<8 : QK GEMM  qk[t][o] (o<1024) = sum_c hf[t][c]*Wqk[o][c] + bqk[o]
// bx>=8: V GEMM   vT[b][o][t]       = sum_c Wv[o][c]*hf[t][c] + bv[o]
__global__ __launch_bounds__(256, 4) void qkv_k(
    const __hip_bfloat16* __restrict__ hf, const __hip_bfloat16* __restrict__ wqk,
    const __hip_bfloat16* __restrict__ wv, const float* __restrict__ bqk,
    const float* __restrict__ bv, __hip_bfloat16* __restrict__ qk,
    __hip_bfloat16* __restrict__ vT) {
  bool isV = blockIdx.x >= 8;
  int m0 = isV ? (blockIdx.x - 8) * 128 : blockIdx.y * 128;
  int n0 = isV ? blockIdx.y * 128 : blockIdx.x * 128;
  const __hip_bfloat16* A  = isV ? wv : hf;   // [m][512]
  const __hip_bfloat16* Bm = isV ? hf : wqk;  // [n][512]

  __shared__ __align__(16) unsigned char smem[34816];  // dbuf(32K) | epi(34K)
  __hip_bfloat16* As  = (__hip_bfloat16*)smem;
  __hip_bfloat16* Bs  = As + 8192;
  __hip_bfloat16* epi = (__hip_bfloat16*)smem;         // [128][136]

  int tid  = threadIdx.x;
  int wvx  = tid >> 6, lane = tid & 63;
  int wr   = (wvx >> 1) * 64, wc = (wvx & 1) * 64;
  int quad = lane >> 4, l16 = lane & 15;

  int srow = wvx * 32 + (lane >> 2);
  int scol = (lane & 3) * 8;
  const __hip_bfloat16* gA0 = A  + (size_t)(m0 + srow) * 512 + scol;
  const __hip_bfloat16* gA1 = gA0 + (size_t)16 * 512;
  const __hip_bfloat16* gB0 = Bm + (size_t)(n0 + srow) * 512 + scol;
  const __hip_bfloat16* gB1 = gB0 + (size_t)16 * 512;

  auto stage = [&](int kk, int bsel) {
    int lb = bsel * 4096 + wvx * 1024;
    gload_lds16(gA0 + kk, &As[lb]);
    gload_lds16(gA1 + kk, &As[lb + 512]);
    gload_lds16(gB0 + kk, &Bs[lb]);
    gload_lds16(gB1 + kk, &Bs[lb + 512]);
  };

  f32x4 acc[4][4] = {};
  stage(0, 0);
  for (int kt = 0; kt < 16; kt++) {
    __syncthreads();
    if (kt + 1 < 16) stage((kt + 1) << 5, (kt + 1) & 1);
    const __hip_bfloat16* Ab = &As[(kt & 1) * 4096];
    const __hip_bfloat16* Bb = &Bs[(kt & 1) * 4096];
    bf16x8 af[4], bfr[4];
#pragma unroll
    for (int i = 0; i < 4; i++)
      af[i] = *(const bf16x8*)&Ab[(wr + i * 16 + l16) * 32 + quad * 8];
#pragma unroll
    for (int j = 0; j < 4; j++)
      bfr[j] = *(const bf16x8*)&Bb[(wc + j * 16 + l16) * 32 + quad * 8];
#pragma unroll
    for (int i = 0; i < 4; i++)
#pragma unroll
      for (int j = 0; j < 4; j++)
        acc[i][j] = __builtin_amdgcn_mfma_f32_16x16x32_bf16(af[i], bfr[j],
                                                            acc[i][j], 0, 0, 0);
  }

  // ---- epilogue via LDS: C-layout -> row-major coalesced ----
  float bj[4], bm[4][4];
  if (!isV) {
#pragma unroll
    for (int j = 0; j < 4; j++) bj[j] = bqk[n0 + wc + j * 16 + l16];
  } else {
#pragma unroll
    for (int i = 0; i < 4; i++)
#pragma unroll
      for (int r = 0; r < 4; r++)
        bm[i][r] = bv[m0 + wr + i * 16 + quad * 4 + r];
  }
  __syncthreads();  // dbuf fragment reads done before epi overwrite
#pragma unroll
  for (int i = 0; i < 4; i++)
#pragma unroll
    for (int j = 0; j < 4; j++)
#pragma unroll
      for (int r = 0; r < 4; r++) {
        int ml = wr + i * 16 + quad * 4 + r;
        int nl = wc + j * 16 + l16;
        float v = acc[i][j][r] + (isV ? bm[i][r] : bj[j]);
        epi[ml * 136 + nl] = __float2bfloat16(v);
      }
  __syncthreads();
  int mr = tid >> 1, h = tid & 1;
  const __hip_bfloat16* rowp = &epi[mr * 136 + h * 64];
  if (!isV) {
    __hip_bfloat16* o = qk + (size_t)(m0 + mr) * 1024 + n0 + h * 64;
#pragma unroll
    for (int c = 0; c < 8; c++)
      *(uint4*)(o + c * 8) = *(const uint4*)(rowp + c * 8);
  } else {
    int b = (n0 + h * 64) >> 12, t = (n0 + h * 64) & 4095;
    __hip_bfloat16* o = vT + ((size_t)(b * 512 + m0 + mr)) * 4096 + t;
#pragma unroll
    for (int c = 0; c < 8; c++)
      *(uint4*)(o + c * 8) = *(const uint4*)(rowp + c * 8);
  }
}

// ==== fused attention v7: Q-in-registers, swapped QK, packed P writes ====
// Grid 1024 = (2b x 4spl: one group per XCD) x 128 q-tiles(32 rows). 8 waves,
// 1 block/CU (VGPR-bound by design: qfrag = 128 VGPR).
// - Q frags live in REGISTERS (loaded once, reused all 8 t) -> QK reads only
//   K from LDS: 1 ds_read/stage vs v6's 3 (v6 was LDS-read-BW-bound: ~92us of
//   139us was ds_read cycles).
// - QK computes mfma(K, Q) = S^T fragments: each lane holds 4 CONSECUTIVE kv
//   for one q -> P written as packed 8B ds_write_b64 (2/lane/t vs 8 scalar
//   b16 with ~8-way conflicts), and PV reads P row-major directly.
// - 16KB private slot/wave: K ring-16 (vmcnt(8) schedule, 8-deep prefetch);
//   V ping-pong (2x4KB) overlays the slot's upper half during PV.
// - 2 barriers per t (Ps visibility / Ps rewrite guard), rest is per-wave
//   vmcnt/lgkmcnt discipline.
__global__ __launch_bounds__(512, 2) void attn_k(
    const __hip_bfloat16* __restrict__ qk, const __hip_bfloat16* __restrict__ vT,
    __hip_bfloat16* __restrict__ part, float* __restrict__ rsum) {
  const float scale = 0.044194173824159216f;
  int bid = blockIdx.x;
  int g = bid & 7;
  int b = g >> 2, spl = g & 3;
  int qtile = bid >> 3;  // 0..127

  const __hip_bfloat16* qkb = qk + (size_t)b * 4194304;
  const __hip_bfloat16* vTb = vT + (size_t)b * 2097152;

  __shared__ __align__(16) unsigned char smem[140288];
  __hip_bfloat16* Ps = (__hip_bfloat16*)smem;        // [32 q][128 kv] swz 8K
  // per-wave 16K slot at 8K + wv*16K: K ring-16 (1KB stages); V 2x4KB overlays
  // elements 4096..8191 (K slots 8..15) during PV
  float* Rs = (float*)(smem + 139264);               // [8][32] 1K

  int tid = threadIdx.x, wv = tid >> 6, lane = tid & 63;
  int quad = lane >> 4, l16 = lane & 15;
  int kvc0 = wv * 16;  // QK wave kv-cols; PV wave d-cols = wv*64

  __hip_bfloat16* slot = (__hip_bfloat16*)(smem + 8192 + wv * 16384);

  // ---- Q fragments -> registers (one-time; 32 x dwordx4, 128 VGPR) ----
  bf16x8 qfrag[2][16];
  {
    const __hip_bfloat16* qrow0 =
        qkb + (size_t)(qtile * 32 + l16) * 1024 + quad * 8;
    const __hip_bfloat16* qrow1 = qrow0 + (size_t)16 * 1024;
#pragma unroll
    for (int s = 0; s < 16; s++) qfrag[0][s] = *(const bf16x8*)(qrow0 + s * 32);
#pragma unroll
    for (int s = 0; s < 16; s++) qfrag[1][s] = *(const bf16x8*)(qrow1 + s * 32);
  }

  // K private staging: stage s = [16 kv (wave's)][32 d], 1 inst, slot s (ring16)
  // LDS[row][chunk] = G[row][chunk ^ (row&3)] (16B chunks within 64B row)
  const __hip_bfloat16* gKw =
      qkb + (size_t)(spl * 1024 + wv * 16 + (lane >> 2)) * 1024 + 512 +
      ((lane & 3) ^ ((lane >> 2) & 3)) * 8;
  auto stageK = [&](int t, int s) {
    gload_lds16(gKw + (size_t)t * 131072 + s * 32, slot + s * 512);
  };

  // V private staging: [64 d (wave's)][32 kv] slab into ping-pong half h
  const __hip_bfloat16* gVw =
      vTb + (size_t)(wv * 64 + (lane >> 2)) * 4096 + spl * 1024 +
      ((lane & 3) ^ ((lane >> 2) & 3)) * 8;
  auto stageV = [&](int t, int sub, int h) {
#pragma unroll
    for (int c = 0; c < 4; c++)
      gload_lds16(gVw + (size_t)t * 128 + sub * 32 + (size_t)(c * 16) * 4096,
                  slot + 4096 + h * 2048 + c * 512);
  };

  f32x4 accS[2] = {};
  f32x4 accO[2][4] = {};
  float rsr[2] = {};

  // prologue: Q loads are in flight; prefill K stages 0..7 of t=0
#pragma unroll
  for (int p = 0; p < 8; p++) stageK(0, p);

  for (int t = 0; t < 8; t++) {
    // ---- QK^T: 16 private BK=32 stages; mfma(K, Q) -> S^T fragments ----
#pragma unroll
    for (int s = 0; s < 16; s++) {
      if (s < 8) {
        stageK(t, s + 8);
        // <=8 outstanding => stage s (and, at t=0 s=0, all Q loads) landed
        asm volatile("s_waitcnt vmcnt(8)" ::: "memory");
      } else if (s == 8)  asm volatile("s_waitcnt vmcnt(7)" ::: "memory");
      else if (s == 9)  asm volatile("s_waitcnt vmcnt(6)" ::: "memory");
      else if (s == 10) asm volatile("s_waitcnt vmcnt(5)" ::: "memory");
      else if (s == 11) asm volatile("s_waitcnt vmcnt(4)" ::: "memory");
      else if (s == 12) asm volatile("s_waitcnt vmcnt(3)" ::: "memory");
      else if (s == 13) asm volatile("s_waitcnt vmcnt(2)" ::: "memory");
      else if (s == 14) asm volatile("s_waitcnt vmcnt(1)" ::: "memory");
      else              asm volatile("s_waitcnt vmcnt(0)" ::: "memory");
      bf16x8 bk = *(const bf16x8*)
          &slot[s * 512 + l16 * 32 + ((quad ^ (l16 & 3)) << 3)];
#pragma unroll
      for (int qg = 0; qg < 2; qg++)
        accS[qg] = __builtin_amdgcn_mfma_f32_16x16x32_bf16(
            bk, qfrag[qg][s], accS[qg], 0, 0, 0);
    }
    // own K reads retired -> upper slot half free for V(0); hides under exp+B
    asm volatile("s_waitcnt lgkmcnt(0)" ::: "memory");
    __builtin_amdgcn_sched_barrier(0);
    stageV(t, 0, 0);
    // ---- exp + rowsum; packed P -> Ps[32][128] (16B-chunk XOR swizzle) ----
#pragma unroll
    for (int qg = 0; qg < 2; qg++) {
      ushort4 pk;
#pragma unroll
      for (int rr = 0; rr < 4; rr++) {
        float p = __expf(accS[qg][rr] * scale);
        rsr[qg] += p;
        union { __hip_bfloat16 h; unsigned short u; } cv;
        cv.h = __float2bfloat16(p);
        ((unsigned short*)&pk)[rr] = cv.u;
      }
      int q = qg * 16 + l16;
      int chunk = (wv * 2 + (quad >> 1)) ^ (q & 7);
      *(ushort4*)&Ps[q * 128 + chunk * 8 + (quad & 1) * 4] = pk;
      accS[qg] = (f32x4){0.f, 0.f, 0.f, 0.f};
    }
    // barrier B: Ps visible to all waves (V(0) DMA stays in flight)
    asm volatile("s_waitcnt lgkmcnt(0)" ::: "memory");
    __builtin_amdgcn_s_barrier();
    asm volatile("" ::: "memory");
    // ---- PV: 4 private V subs (ping-pong); per-wave waits only ----
#pragma unroll
    for (int sub = 0; sub < 4; sub++) {
      if (sub > 0) {
        // prev sub's ds_reads retired before DMA may overwrite that half
        asm volatile("s_waitcnt lgkmcnt(0)" ::: "memory");
        __builtin_amdgcn_sched_barrier(0);
      }
      if (sub < 3) {
        stageV(t, sub + 1, (sub + 1) & 1);
        asm volatile("s_waitcnt vmcnt(4)" ::: "memory");  // V(sub) landed
      } else if (t + 1 < 8) {
        // K(t+1) prefill -> slots 0..7 (lower half; V(3) lives in upper)
#pragma unroll
        for (int p = 0; p < 8; p++) stageK(t + 1, p);
        asm volatile("s_waitcnt vmcnt(8)" ::: "memory");  // V(3) landed
      } else {
        asm volatile("s_waitcnt vmcnt(0)" ::: "memory");
      }
      const __hip_bfloat16* Vb = slot + 4096 + (sub & 1) * 2048;
      bf16x8 pa[2], bvf[4];
#pragma unroll
      for (int qg = 0; qg < 2; qg++) {
        int rq = qg * 16 + l16;
        pa[qg] = *(const bf16x8*)
            &Ps[rq * 128 + (((sub * 4 + quad) ^ (rq & 7)) << 3)];
      }
#pragma unroll
      for (int dj = 0; dj < 4; dj++)
        bvf[dj] = *(const bf16x8*)
            &Vb[(dj * 16 + l16) * 32 + ((quad ^ (l16 & 3)) << 3)];
#pragma unroll
      for (int dj = 0; dj < 4; dj++)
#pragma unroll
        for (int qg = 0; qg < 2; qg++)
          accO[qg][dj] = __builtin_amdgcn_mfma_f32_16x16x32_bf16(
              pa[qg], bvf[dj], accO[qg][dj], 0, 0, 0);
    }
    // barrier C: all PV Ps-reads retired block-wide before next-t exp rewrite
    asm volatile("s_waitcnt lgkmcnt(0)" ::: "memory");
    __builtin_amdgcn_s_barrier();
    asm volatile("" ::: "memory");
  }

  // ---- epilogue: partials (bf16) + per-row expsum ----
  size_t pbase = ((size_t)(spl * 2 + b) * 4096 + qtile * 32) * 512;
#pragma unroll
  for (int qg = 0; qg < 2; qg++)
#pragma unroll
    for (int rr = 0; rr < 4; rr++) {
      int row = qg * 16 + quad * 4 + rr;
#pragma unroll
      for (int dj = 0; dj < 4; dj++)
        part[pbase + (size_t)row * 512 + wv * 64 + dj * 16 + l16] =
            __float2bfloat16(accO[qg][dj][rr]);
    }
  // rowsum: lane holds sum over its 4 kv (+t,+rr) for q=qg*16+l16; reduce quad
#pragma unroll
  for (int qg = 0; qg < 2; qg++) {
    rsr[qg] += __shfl_xor(rsr[qg], 16);
    rsr[qg] += __shfl_xor(rsr[qg], 32);
  }
  if (quad == 0) {
#pragma unroll
    for (int qg = 0; qg < 2; qg++)
      Rs[wv * 32 + qg * 16 + l16] = rsr[qg];
  }
  __syncthreads();
  if (tid < 32) {
    float s = 0.f;
#pragma unroll
    for (int w = 0; w < 8; w++) s += Rs[w * 32 + tid];
    rsum[spl * 8192 + b * 4096 + qtile * 32 + tid] = s;
  }
}

// ---- fold 4 kv-split partials + expsums, normalize -> obuf ----
__global__ __launch_bounds__(256) void reduce2_k(
    const __hip_bfloat16* __restrict__ part, const float* __restrict__ rsum,
    __hip_bfloat16* __restrict__ obuf) {
  size_t i8 = (size_t)blockIdx.x * 256 + threadIdx.x;
  size_t perb = 262144;  // 4096*512/8 vectors per batch
  size_t b = i8 / perb, r = i8 - b * perb;
  int t = (int)(r >> 6);
  float ps = rsum[b * 4096 + t] + rsum[8192 + b * 4096 + t] +
             rsum[16384 + b * 4096 + t] + rsum[24576 + b * 4096 + t];
  float inv = 1.f / ps;
  float acc[8] = {};
#pragma unroll
  for (int sp = 0; sp < 4; sp++) {
    bf16x8 v = ((const bf16x8*)part)[(sp * 2 + b) * perb + r];
#pragma unroll
    for (int l = 0; l < 8; l++) acc[l] += (float)v[l];
  }
  bf16x8 o;
#pragma unroll
  for (int l = 0; l < 8; l++) o[l] = (__bf16)(acc[l] * inv);
  ((bf16x8*)obuf)[b * perb + r] = o;
}

// ====== out-proj, 64x128 tiles (512 blocks = 2/CU vs old 256 = 1/CU) ======
// out[b][c][t] = x[b][c][t] + bf16(sum_o Wo[c][o]*obuf[b][t][o] + bo[c])
__global__ __launch_bounds__(256, 2) void oproj_k(
    const __hip_bfloat16* __restrict__ Wo, const __hip_bfloat16* __restrict__ O,
    float* __restrict__ out, const float* __restrict__ bias,
    const float* __restrict__ resid) {
  int m0 = blockIdx.y * 64, n0 = blockIdx.x * 128, bb = blockIdx.z;
  O += (size_t)bb * 4096 * 512;
  size_t cbase = (size_t)bb * 512 * 4096;

  __shared__ __align__(16) unsigned char smem[24576];  // A 2x4K | B 2x8K; epi
  __hip_bfloat16* As  = (__hip_bfloat16*)smem;          // 2 x [64][32]
  __hip_bfloat16* Bs  = As + 4096;                      // 2 x [128][32]
  __hip_bfloat16* epi = (__hip_bfloat16*)smem;          // [64][136] = 17.4K

  int tid = threadIdx.x, wv = tid >> 6, lane = tid & 63;
  int wr = (wv >> 1) * 32, wc = (wv & 1) * 64;
  int quad = lane >> 4, l16 = lane & 15;

  int lr = lane >> 2, scol = (lane & 3) * 8;
  const __hip_bfloat16* gA  = Wo + (size_t)(m0 + wv * 16 + lr) * 512 + scol;
  const __hip_bfloat16* gB0 = O  + (size_t)(n0 + wv * 32 + lr) * 512 + scol;
  const __hip_bfloat16* gB1 = gB0 + (size_t)16 * 512;

  auto stage = [&](int kk, int bsel) {
    gload_lds16(gA + kk, &As[bsel * 2048 + wv * 512]);
    gload_lds16(gB0 + kk, &Bs[bsel * 4096 + wv * 1024]);
    gload_lds16(gB1 + kk, &Bs[bsel * 4096 + wv * 1024 + 512]);
  };

  f32x4 acc[2][4] = {};
  stage(0, 0);
  for (int kt = 0; kt < 16; kt++) {
    __syncthreads();
    if (kt + 1 < 16) stage((kt + 1) << 5, (kt + 1) & 1);
    const __hip_bfloat16* Ab = &As[(kt & 1) * 2048];
    const __hip_bfloat16* Bb = &Bs[(kt & 1) * 4096];
    bf16x8 af[2], bfr[4];
#pragma unroll
    for (int i = 0; i < 2; i++)
      af[i] = *(const bf16x8*)&Ab[(wr + i * 16 + l16) * 32 + quad * 8];
#pragma unroll
    for (int j = 0; j < 4; j++)
      bfr[j] = *(const bf16x8*)&Bb[(wc + j * 16 + l16) * 32 + quad * 8];
#pragma unroll
    for (int i = 0; i < 2; i++)
#pragma unroll
      for (int j = 0; j < 4; j++)
        acc[i][j] = __builtin_amdgcn_mfma_f32_16x16x32_bf16(af[i], bfr[j],
                                                            acc[i][j], 0, 0, 0);
  }

  float pre[2][4];
#pragma unroll
  for (int i = 0; i < 2; i++)
#pragma unroll
    for (int r = 0; r < 4; r++)
      pre[i][r] = bias[m0 + wr + i * 16 + quad * 4 + r];
  __syncthreads();
#pragma unroll
  for (int i = 0; i < 2; i++)
#pragma unroll
    for (int j = 0; j < 4; j++)
#pragma unroll
      for (int r = 0; r < 4; r++)
        epi[(wr + i * 16 + quad * 4 + r) * 136 + wc + j * 16 + l16] =
            __float2bfloat16(acc[i][j][r] + pre[i][r]);
  __syncthreads();
  int mr = tid >> 2, seg = tid & 3;  // 4 threads/row, 32 elems each
  const __hip_bfloat16* rowp = &epi[mr * 136 + seg * 32];
  size_t obase = cbase + (size_t)(m0 + mr) * 4096 + n0 + seg * 32;
#pragma unroll
  for (int c = 0; c < 4; c++) {
    bf16x8 val = *(const bf16x8*)(rowp + c * 8);
    size_t idx = obase + c * 8;
    float4 r0 = *(const float4*)&resid[idx];
    float4 r1 = *(const float4*)&resid[idx + 4];
    float4 o0, o1;
    o0.x = r0.x + (float)val[0]; o0.y = r0.y + (float)val[1];
    o0.z = r0.z + (float)val[2]; o0.w = r0.w + (float)val[3];
    o1.x = r1.x + (float)val[4]; o1.y = r1.y + (float)val[5];
    o1.z = r1.z + (float)val[6]; o1.w = r1.w + (float)val[7];
    *(float4*)&out[idx] = o0;
    *(float4*)&out[idx + 4] = o1;
  }
}

extern "C" void kernel_launch(void* const* d_in, const int* in_sizes, int n_in,
                              void* d_out, int out_size, void* d_ws,
                              size_t ws_size, hipStream_t stream) {
  const float* xp  = (const float*)d_in[0];
  const float* gwp = (const float*)d_in[1];
  const float* gbp = (const float*)d_in[2];
  const float* wqp = (const float*)d_in[3];
  const float* bqp = (const float*)d_in[4];
  const float* wkp = (const float*)d_in[5];
  const float* bkp = (const float*)d_in[6];
  const float* wvp = (const float*)d_in[7];
  const float* bvp = (const float*)d_in[8];
  const float* wop = (const float*)d_in[9];
  const float* bop = (const float*)d_in[10];
  float* outp = (float*)d_out;

  char* w = (char*)d_ws;
  size_t off = 0;
  auto alloc = [&](size_t bytes) {
    void* p = w + off;
    off += (bytes + 255) & ~(size_t)255;
    return p;
  };
  float* stats         = (float*)alloc(64 * 2 * sizeof(float));
  __hip_bfloat16* hf   = (__hip_bfloat16*)alloc((size_t)2 * 4096 * 512 * 2);
  __hip_bfloat16* wqkb = (__hip_bfloat16*)alloc((size_t)1024 * 512 * 2);
  __hip_bfloat16* wvb  = (__hip_bfloat16*)alloc((size_t)512 * 512 * 2);
  __hip_bfloat16* wob  = (__hip_bfloat16*)alloc((size_t)512 * 512 * 2);
  float* bqk           = (float*)alloc(1024 * sizeof(float));
  float* rsum          = (float*)alloc((size_t)4 * 2 * 4096 * sizeof(float));
  __hip_bfloat16* qk   = (__hip_bfloat16*)alloc((size_t)2 * 4096 * 1024 * 2);
  __hip_bfloat16* vT   = (__hip_bfloat16*)alloc((size_t)2 * 512 * 4096 * 2);
  __hip_bfloat16* obuf = (__hip_bfloat16*)alloc((size_t)2 * 4096 * 512 * 2);
  __hip_bfloat16* part = (__hip_bfloat16*)alloc((size_t)8 * 4096 * 512 * 2);

  // prelude: 4096 cvt blocks + 64 gn_stats blocks + 1 bcat block
  prelude_k<<<4161, 256, 0, stream>>>(wqp, wkp, wvp, wop, wqkb, wvb, wob,
                                      bqp, bkp, bqk, xp, stats);

  gn_apply_k<<<dim3(8, 64, 2), 256, 0, stream>>>(xp, stats, gwp, gbp, hf);

  // fused QKV: qk[8192][1024] and vT[2][512][4096]
  qkv_k<<<dim3(12, 64, 1), 256, 0, stream>>>(hf, wqkb, wvb, bqk, bvp, qk, vT);

  // fused attention v7: Q-in-regs, swapped QK, wave-private deep pipelines
  attn_k<<<1024, 512, 0, stream>>>(qk, vT, part, rsum);

  // fold 4 partials + expsums, normalize -> obuf
  reduce2_k<<<2048, 256, 0, stream>>>(part, rsum, obuf);

  // out[b][c][t] = x + Wo*O + bo  (64x128 tiles, 512 blocks)
  oproj_k<<<dim3(32, 8, 2), 256, 0, stream>>>(wob, obuf, outp, bop, xp);
}

// Round 8
// 257.336 us; speedup vs baseline: 1.2722x; 1.2722x over previous
//
#include <hip/hip_runtime.h>
#include <hip/hip_bf16.h>

// Problem constants: B=2, C=512, H=W=64 -> N=4096, G=32 (16 ch/group), EPS=1e-6.

typedef float f32x4 __attribute__((ext_vector_type(4)));
typedef __bf16 bf16x8 __attribute__((ext_vector_type(8)));

typedef const __attribute__((address_space(1))) unsigned char* gas_p;
typedef __attribute__((address_space(3))) unsigned char* las_p;

__device__ __forceinline__ void gload_lds16(const void* g, void* l) {
  // async DMA: each lane contributes 16B; LDS dst = wave-uniform base + lane*16
  __builtin_amdgcn_global_load_lds((gas_p)g, (las_p)l, 16, 0, 0);
}

// ====== prelude: weight cvt (4x1024 blocks) | gn_stats (64) | bcat (1) ======
__global__ __launch_bounds__(256) void prelude_k(
    const float* __restrict__ wq, const float* __restrict__ wk,
    const float* __restrict__ wv, const float* __restrict__ wo,
    __hip_bfloat16* __restrict__ wqkb, __hip_bfloat16* __restrict__ wvb,
    __hip_bfloat16* __restrict__ wob, const float* __restrict__ bq,
    const float* __restrict__ bk, float* __restrict__ bqk,
    const float* __restrict__ x, float* __restrict__ stats) {
  int bid = blockIdx.x;
  if (bid < 4096) {
    const float* src;
    __hip_bfloat16* dst;
    if (bid < 1024)      { src = wq; dst = wqkb; }
    else if (bid < 2048) { src = wk; dst = wqkb + 262144; }
    else if (bid < 3072) { src = wv; dst = wvb; }
    else                 { src = wo; dst = wob; }
    int i = (bid & 1023) * 256 + threadIdx.x;  // 1024*256 = 262144 = 512*512
    dst[i] = __float2bfloat16(src[i]);
    return;
  }
  if (bid < 4160) {  // gn_stats: one block per (b,g)
    int bg = bid - 4096;
    const float4* p = (const float4*)(x + (size_t)bg * 65536);
    float s = 0.f, s2 = 0.f;
    for (int i = threadIdx.x; i < 16384; i += 256) {
      float4 v = p[i];
      s  += v.x + v.y + v.z + v.w;
      s2 += v.x * v.x + v.y * v.y + v.z * v.z + v.w * v.w;
    }
#pragma unroll
    for (int off = 32; off > 0; off >>= 1) {
      s  += __shfl_xor(s, off);
      s2 += __shfl_xor(s2, off);
    }
    __shared__ float rs[4], rs2[4];
    int wid = threadIdx.x >> 6, lane = threadIdx.x & 63;
    if (lane == 0) { rs[wid] = s; rs2[wid] = s2; }
    __syncthreads();
    if (threadIdx.x == 0) {
      float S  = rs[0] + rs[1] + rs[2] + rs[3];
      float S2 = rs2[0] + rs2[1] + rs2[2] + rs2[3];
      float mean = S * (1.f / 65536.f);
      float var  = S2 * (1.f / 65536.f) - mean * mean;
      stats[bg * 2]     = mean;
      stats[bg * 2 + 1] = rsqrtf(var + 1e-6f);
    }
    return;
  }
  // bcat
  for (int j = threadIdx.x; j < 1024; j += 256)
    bqk[j] = (j < 512) ? bq[j] : bk[j - 512];
}

// ------- GroupNorm apply + transpose, vectorized: x fp32 -> hf bf16 [b][n][c]
__global__ __launch_bounds__(256) void gn_apply_k(const float* __restrict__ x,
                                                  const float* __restrict__ stats,
                                                  const float* __restrict__ gw,
                                                  const float* __restrict__ gb,
                                                  __hip_bfloat16* __restrict__ hf) {
  int c0 = blockIdx.x * 64, n0 = blockIdx.y * 64, b = blockIdx.z;
  __shared__ float tile[64][65];
  int tid = threadIdx.x;
  int cl = tid >> 2, q = tid & 3;
  int c = c0 + cl;
  float mean = stats[(b * 32 + (c >> 4)) * 2];
  float rstd = stats[(b * 32 + (c >> 4)) * 2 + 1];
  float sc = rstd * gw[c];
  float sh = gb[c] - mean * sc;
  const float* xr = x + ((size_t)(b * 512 + c0 + cl)) * 4096 + n0 + q * 16;
#pragma unroll
  for (int j = 0; j < 4; j++) {
    float4 v = *(const float4*)(xr + 4 * j);
    int n = q * 16 + 4 * j;
    tile[cl][n]     = v.x * sc + sh;
    tile[cl][n + 1] = v.y * sc + sh;
    tile[cl][n + 2] = v.z * sc + sh;
    tile[cl][n + 3] = v.w * sc + sh;
  }
  __syncthreads();
  int nl = tid >> 2, ch = q * 16;
  bf16x8 o0, o1;
#pragma unroll
  for (int l = 0; l < 8; l++) {
    o0[l] = (__bf16)tile[ch + l][nl];
    o1[l] = (__bf16)tile[ch + 8 + l][nl];
  }
  __hip_bfloat16* op = hf + ((size_t)(b * 4096 + n0 + nl)) * 512 + c0 + ch;
  *(uint4*)op = *(uint4*)&o0;
  *(uint4*)(op + 8) = *(uint4*)&o1;
}

// ============ fused QKV (double-buffered DMA + LDS epilogue) ============
// bx<8 : QK GEMM  qk[t][o] (o<1024) = sum_c hf[t][c]*Wqk[o][c] + bqk[o]
// bx>=8: V GEMM   vT[b][o][t]       = sum_c Wv[o][c]*hf[t][c] + bv[o]
__global__ __launch_bounds__(256, 4) void qkv_k(
    const __hip_bfloat16* __restrict__ hf, const __hip_bfloat16* __restrict__ wqk,
    const __hip_bfloat16* __restrict__ wv, const float* __restrict__ bqk,
    const float* __restrict__ bv, __hip_bfloat16* __restrict__ qk,
    __hip_bfloat16* __restrict__ vT) {
  bool isV = blockIdx.x >= 8;
  int m0 = isV ? (blockIdx.x - 8) * 128 : blockIdx.y * 128;
  int n0 = isV ? blockIdx.y * 128 : blockIdx.x * 128;
  const __hip_bfloat16* A  = isV ? wv : hf;   // [m][512]
  const __hip_bfloat16* Bm = isV ? hf : wqk;  // [n][512]

  __shared__ __align__(16) unsigned char smem[34816];  // dbuf(32K) | epi(34K)
  __hip_bfloat16* As  = (__hip_bfloat16*)smem;
  __hip_bfloat16* Bs  = As + 8192;
  __hip_bfloat16* epi = (__hip_bfloat16*)smem;         // [128][136]

  int tid  = threadIdx.x;
  int wvx  = tid >> 6, lane = tid & 63;
  int wr   = (wvx >> 1) * 64, wc = (wvx & 1) * 64;
  int quad = lane >> 4, l16 = lane & 15;

  int srow = wvx * 32 + (lane >> 2);
  int scol = (lane & 3) * 8;
  const __hip_bfloat16* gA0 = A  + (size_t)(m0 + srow) * 512 + scol;
  const __hip_bfloat16* gA1 = gA0 + (size_t)16 * 512;
  const __hip_bfloat16* gB0 = Bm + (size_t)(n0 + srow) * 512 + scol;
  const __hip_bfloat16* gB1 = gB0 + (size_t)16 * 512;

  auto stage = [&](int kk, int bsel) {
    int lb = bsel * 4096 + wvx * 1024;
    gload_lds16(gA0 + kk, &As[lb]);
    gload_lds16(gA1 + kk, &As[lb + 512]);
    gload_lds16(gB0 + kk, &Bs[lb]);
    gload_lds16(gB1 + kk, &Bs[lb + 512]);
  };

  f32x4 acc[4][4] = {};
  stage(0, 0);
  for (int kt = 0; kt < 16; kt++) {
    __syncthreads();
    if (kt + 1 < 16) stage((kt + 1) << 5, (kt + 1) & 1);
    const __hip_bfloat16* Ab = &As[(kt & 1) * 4096];
    const __hip_bfloat16* Bb = &Bs[(kt & 1) * 4096];
    bf16x8 af[4], bfr[4];
#pragma unroll
    for (int i = 0; i < 4; i++)
      af[i] = *(const bf16x8*)&Ab[(wr + i * 16 + l16) * 32 + quad * 8];
#pragma unroll
    for (int j = 0; j < 4; j++)
      bfr[j] = *(const bf16x8*)&Bb[(wc + j * 16 + l16) * 32 + quad * 8];
#pragma unroll
    for (int i = 0; i < 4; i++)
#pragma unroll
      for (int j = 0; j < 4; j++)
        acc[i][j] = __builtin_amdgcn_mfma_f32_16x16x32_bf16(af[i], bfr[j],
                                                            acc[i][j], 0, 0, 0);
  }

  // ---- epilogue via LDS: C-layout -> row-major coalesced ----
  float bj[4], bm[4][4];
  if (!isV) {
#pragma unroll
    for (int j = 0; j < 4; j++) bj[j] = bqk[n0 + wc + j * 16 + l16];
  } else {
#pragma unroll
    for (int i = 0; i < 4; i++)
#pragma unroll
      for (int r = 0; r < 4; r++)
        bm[i][r] = bv[m0 + wr + i * 16 + quad * 4 + r];
  }
  __syncthreads();  // dbuf fragment reads done before epi overwrite
#pragma unroll
  for (int i = 0; i < 4; i++)
#pragma unroll
    for (int j = 0; j < 4; j++)
#pragma unroll
      for (int r = 0; r < 4; r++) {
        int ml = wr + i * 16 + quad * 4 + r;
        int nl = wc + j * 16 + l16;
        float v = acc[i][j][r] + (isV ? bm[i][r] : bj[j]);
        epi[ml * 136 + nl] = __float2bfloat16(v);
      }
  __syncthreads();
  int mr = tid >> 1, h = tid & 1;
  const __hip_bfloat16* rowp = &epi[mr * 136 + h * 64];
  if (!isV) {
    __hip_bfloat16* o = qk + (size_t)(m0 + mr) * 1024 + n0 + h * 64;
#pragma unroll
    for (int c = 0; c < 8; c++)
      *(uint4*)(o + c * 8) = *(const uint4*)(rowp + c * 8);
  } else {
    int b = (n0 + h * 64) >> 12, t = (n0 + h * 64) & 4095;
    __hip_bfloat16* o = vT + ((size_t)(b * 512 + m0 + mr)) * 4096 + t;
#pragma unroll
    for (int c = 0; c < 8; c++)
      *(uint4*)(o + c * 8) = *(const uint4*)(rowp + c * 8);
  }
}

// ------------- QK^T GEMM: expS + atomic-free row sums (proven R0 path) -----
__global__ __launch_bounds__(256, 4) void qkexp_k(
    const __hip_bfloat16* __restrict__ A, const __hip_bfloat16* __restrict__ Bm,
    __hip_bfloat16* __restrict__ Cout, float* __restrict__ psums) {
  int bx = blockIdx.x, by = blockIdx.y, bb = blockIdx.z;
  const float scale = 0.044194173824159216f;
  A  += (size_t)bb * 4096 * 1024;
  Bm += (size_t)bb * 4096 * 1024 + 512;
  size_t cbase = (size_t)bb * 4096 * 4096;
  int m0 = by * 128, n0 = bx * 128;

  __shared__ __align__(16) unsigned char smem[33792];  // dbuf(32K) | psum2(1K)
  __hip_bfloat16* As  = (__hip_bfloat16*)smem;
  __hip_bfloat16* Bs  = As + 8192;
  float* psum2 = (float*)(smem + 32768);               // [2][128]

  int tid  = threadIdx.x;
  int wv   = tid >> 6, lane = tid & 63;
  int wr   = (wv >> 1) * 64, wc = (wv & 1) * 64;
  int quad = lane >> 4, l16 = lane & 15;

  int srow = wv * 32 + (lane >> 2);
  int scol = (lane & 3) * 8;
  const __hip_bfloat16* gA0 = A  + (size_t)(m0 + srow) * 1024 + scol;
  const __hip_bfloat16* gA1 = gA0 + (size_t)16 * 1024;
  const __hip_bfloat16* gB0 = Bm + (size_t)(n0 + srow) * 1024 + scol;
  const __hip_bfloat16* gB1 = gB0 + (size_t)16 * 1024;

  auto stage = [&](int kk, int bsel) {
    int lb = bsel * 4096 + wv * 1024;
    gload_lds16(gA0 + kk, &As[lb]);
    gload_lds16(gA1 + kk, &As[lb + 512]);
    gload_lds16(gB0 + kk, &Bs[lb]);
    gload_lds16(gB1 + kk, &Bs[lb + 512]);
  };

  f32x4 acc[4][4] = {};
  stage(0, 0);
  for (int kt = 0; kt < 16; kt++) {
    __syncthreads();
    if (kt + 1 < 16) stage((kt + 1) << 5, (kt + 1) & 1);
    const __hip_bfloat16* Ab = &As[(kt & 1) * 4096];
    const __hip_bfloat16* Bb = &Bs[(kt & 1) * 4096];
    bf16x8 af[4], bfr[4];
#pragma unroll
    for (int i = 0; i < 4; i++)
      af[i] = *(const bf16x8*)&Ab[(wr + i * 16 + l16) * 32 + quad * 8];
#pragma unroll
    for (int j = 0; j < 4; j++)
      bfr[j] = *(const bf16x8*)&Bb[(wc + j * 16 + l16) * 32 + quad * 8];
#pragma unroll
    for (int i = 0; i < 4; i++)
#pragma unroll
      for (int j = 0; j < 4; j++)
        acc[i][j] = __builtin_amdgcn_mfma_f32_16x16x32_bf16(af[i], bfr[j],
                                                            acc[i][j], 0, 0, 0);
  }

  // direct scattered stores + register row-sum reduction (measured 57-59 us;
  // LDS-staged variant measured 65.6 us -> keep direct)
  float s[4][4];
#pragma unroll
  for (int i = 0; i < 4; i++)
#pragma unroll
    for (int r = 0; r < 4; r++) s[i][r] = 0.f;
#pragma unroll
  for (int i = 0; i < 4; i++)
#pragma unroll
    for (int j = 0; j < 4; j++)
#pragma unroll
      for (int r = 0; r < 4; r++) {
        int m = m0 + wr + i * 16 + quad * 4 + r;
        int n = n0 + wc + j * 16 + l16;
        float v = __expf(acc[i][j][r] * scale);
        Cout[cbase + (size_t)m * 4096 + n] = __float2bfloat16(v);
        s[i][r] += v;
      }
#pragma unroll
  for (int off = 1; off < 16; off <<= 1)
#pragma unroll
    for (int i = 0; i < 4; i++)
#pragma unroll
      for (int r = 0; r < 4; r++) s[i][r] += __shfl_xor(s[i][r], off);
  if (l16 == 0) {
#pragma unroll
    for (int i = 0; i < 4; i++)
#pragma unroll
      for (int r = 0; r < 4; r++)
        psum2[(wv & 1) * 128 + wr + i * 16 + quad * 4 + r] = s[i][r];
  }
  __syncthreads();
  if (tid < 128)
    psums[(size_t)bx * 8192 + bb * 4096 + m0 + tid] =
        psum2[tid] + psum2[128 + tid];
}

// ===== PV full-K (kspl=1): obuf[b][t][d] = (S . V) * inv(rowsum) ===========
// 64x128 tiles, K=4096 in 64 dbuf BK=64 stages. psums are COMPLETE before
// this launches (qkexp wrote them) -> normalize inline, write obuf directly.
// Eliminates the split-K part buffer (32MB W + 32MB R) and reduce_k entirely.
// XCD remap co-locates the 4 d-tiles of each (m,b) so the S A-panel is
// L2-shared (same trick as the proven R0 pv_k).
__global__ __launch_bounds__(256, 2) void pv_k(
    const __hip_bfloat16* __restrict__ S, const __hip_bfloat16* __restrict__ vT,
    const float* __restrict__ psums, __hip_bfloat16* __restrict__ obuf) {
  int f = blockIdx.x;
  int xcd = f & 7, sidx = f >> 3;
  int bx = sidx & 3;
  int g = xcd + 8 * (sidx >> 2);  // 0..127
  int by = g & 63, b = g >> 6;
  int m0 = by * 64, n0 = bx * 128;
  const __hip_bfloat16* A  = S  + (size_t)b * 4096 * 4096;
  const __hip_bfloat16* Bv = vT + (size_t)b * 512 * 4096;

  __shared__ __align__(16) unsigned char smem[49664];
  __hip_bfloat16* As  = (__hip_bfloat16*)smem;            // 2 x [64][64]  16K
  __hip_bfloat16* Bs  = (__hip_bfloat16*)(smem + 16384);  // 2 x [128][64] 32K
  __hip_bfloat16* epi = (__hip_bfloat16*)smem;            // [64][136] 17.4K
  float* inv = (float*)(smem + 49152);                    // [64]

  int tid = threadIdx.x, wv = tid >> 6, lane = tid & 63;
  int wr = (wv >> 1) * 32, wc = (wv & 1) * 64;
  int quad = lane >> 4, l16 = lane & 15;

  // staging: 64B-chunked rows, 8 rows/wave/inst, XOR chunk swizzle
  // LDS[r][c] = G[r][c ^ (r&7)] (16B chunks) -> b128 frag reads spread banks
  int srow8 = lane >> 3;
  int schk = ((lane & 7) ^ srow8) * 8;
  const __hip_bfloat16* gA0 = A  + (size_t)(m0 + wv * 8 + srow8) * 4096 + schk;
  const __hip_bfloat16* gA1 = gA0 + (size_t)32 * 4096;
  const __hip_bfloat16* gB0 = Bv + (size_t)(n0 + wv * 8 + srow8) * 4096 + schk;

  auto stage = [&](int kk, int bsel) {
    gload_lds16(gA0 + kk, &As[bsel * 4096 + wv * 512]);
    gload_lds16(gA1 + kk, &As[bsel * 4096 + wv * 512 + 2048]);
#pragma unroll
    for (int r = 0; r < 4; r++)
      gload_lds16(gB0 + kk + (size_t)(r * 32) * 4096,
                  &Bs[bsel * 8192 + wv * 512 + r * 2048]);
  };

  f32x4 acc[2][4] = {};
  stage(0, 0);
  // rowsum inverse for this block's 64 q-rows (32 n-tile partials each)
  if (tid < 64) {
    float ssum = 0.f;
#pragma unroll
    for (int j = 0; j < 32; j++)
      ssum += psums[(size_t)j * 8192 + b * 4096 + m0 + tid];
    inv[tid] = 1.f / ssum;
  }
  for (int kt = 0; kt < 64; kt++) {
    __syncthreads();
    if (kt + 1 < 64) stage((kt + 1) << 6, (kt + 1) & 1);
    const __hip_bfloat16* Ab = &As[(kt & 1) * 4096];
    const __hip_bfloat16* Bb = &Bs[(kt & 1) * 8192];
#pragma unroll
    for (int kk = 0; kk < 2; kk++) {
      bf16x8 af[2], bfr[4];
#pragma unroll
      for (int i = 0; i < 2; i++) {
        int r = wr + i * 16 + l16;
        af[i] = *(const bf16x8*)&Ab[r * 64 + (((kk * 4 + quad) ^ (r & 7)) << 3)];
      }
#pragma unroll
      for (int j = 0; j < 4; j++) {
        int r = wc + j * 16 + l16;
        bfr[j] = *(const bf16x8*)&Bb[r * 64 + (((kk * 4 + quad) ^ (r & 7)) << 3)];
      }
#pragma unroll
      for (int i = 0; i < 2; i++)
#pragma unroll
        for (int j = 0; j < 4; j++)
          acc[i][j] = __builtin_amdgcn_mfma_f32_16x16x32_bf16(af[i], bfr[j],
                                                              acc[i][j], 0, 0, 0);
    }
  }
  float iv[2][4];
#pragma unroll
  for (int i = 0; i < 2; i++)
#pragma unroll
    for (int r = 0; r < 4; r++) iv[i][r] = inv[wr + i * 16 + quad * 4 + r];
  __syncthreads();  // frag reads done before epi overwrite
#pragma unroll
  for (int i = 0; i < 2; i++)
#pragma unroll
    for (int j = 0; j < 4; j++)
#pragma unroll
      for (int r = 0; r < 4; r++)
        epi[(wr + i * 16 + quad * 4 + r) * 136 + wc + j * 16 + l16] =
            __float2bfloat16(acc[i][j][r] * iv[i][r]);
  __syncthreads();
  int mr = tid >> 2, seg = tid & 3;  // 4 threads/row, 32 elems each
  const __hip_bfloat16* rowp = &epi[mr * 136 + seg * 32];
  __hip_bfloat16* o =
      obuf + ((size_t)(b * 4096 + m0 + mr)) * 512 + n0 + seg * 32;
#pragma unroll
  for (int c = 0; c < 4; c++)
    *(uint4*)(o + c * 8) = *(const uint4*)(rowp + c * 8);
}

// ====== out-proj, 64x128 tiles (512 blocks = 2/CU) ======
// out[b][c][t] = x[b][c][t] + bf16(sum_o Wo[c][o]*obuf[b][t][o] + bo[c])
__global__ __launch_bounds__(256, 2) void oproj_k(
    const __hip_bfloat16* __restrict__ Wo, const __hip_bfloat16* __restrict__ O,
    float* __restrict__ out, const float* __restrict__ bias,
    const float* __restrict__ resid) {
  int m0 = blockIdx.y * 64, n0 = blockIdx.x * 128, bb = blockIdx.z;
  O += (size_t)bb * 4096 * 512;
  size_t cbase = (size_t)bb * 512 * 4096;

  __shared__ __align__(16) unsigned char smem[24576];  // A 2x4K | B 2x8K; epi
  __hip_bfloat16* As  = (__hip_bfloat16*)smem;          // 2 x [64][32]
  __hip_bfloat16* Bs  = As + 4096;                      // 2 x [128][32]
  __hip_bfloat16* epi = (__hip_bfloat16*)smem;          // [64][136] = 17.4K

  int tid = threadIdx.x, wv = tid >> 6, lane = tid & 63;
  int wr = (wv >> 1) * 32, wc = (wv & 1) * 64;
  int quad = lane >> 4, l16 = lane & 15;

  int lr = lane >> 2, scol = (lane & 3) * 8;
  const __hip_bfloat16* gA  = Wo + (size_t)(m0 + wv * 16 + lr) * 512 + scol;
  const __hip_bfloat16* gB0 = O  + (size_t)(n0 + wv * 32 + lr) * 512 + scol;
  const __hip_bfloat16* gB1 = gB0 + (size_t)16 * 512;

  auto stage = [&](int kk, int bsel) {
    gload_lds16(gA + kk, &As[bsel * 2048 + wv * 512]);
    gload_lds16(gB0 + kk, &Bs[bsel * 4096 + wv * 1024]);
    gload_lds16(gB1 + kk, &Bs[bsel * 4096 + wv * 1024 + 512]);
  };

  f32x4 acc[2][4] = {};
  stage(0, 0);
  for (int kt = 0; kt < 16; kt++) {
    __syncthreads();
    if (kt + 1 < 16) stage((kt + 1) << 5, (kt + 1) & 1);
    const __hip_bfloat16* Ab = &As[(kt & 1) * 2048];
    const __hip_bfloat16* Bb = &Bs[(kt & 1) * 4096];
    bf16x8 af[2], bfr[4];
#pragma unroll
    for (int i = 0; i < 2; i++)
      af[i] = *(const bf16x8*)&Ab[(wr + i * 16 + l16) * 32 + quad * 8];
#pragma unroll
    for (int j = 0; j < 4; j++)
      bfr[j] = *(const bf16x8*)&Bb[(wc + j * 16 + l16) * 32 + quad * 8];
#pragma unroll
    for (int i = 0; i < 2; i++)
#pragma unroll
      for (int j = 0; j < 4; j++)
        acc[i][j] = __builtin_amdgcn_mfma_f32_16x16x32_bf16(af[i], bfr[j],
                                                            acc[i][j], 0, 0, 0);
  }

  float pre[2][4];
#pragma unroll
  for (int i = 0; i < 2; i++)
#pragma unroll
    for (int r = 0; r < 4; r++)
      pre[i][r] = bias[m0 + wr + i * 16 + quad * 4 + r];
  __syncthreads();
#pragma unroll
  for (int i = 0; i < 2; i++)
#pragma unroll
    for (int j = 0; j < 4; j++)
#pragma unroll
      for (int r = 0; r < 4; r++)
        epi[(wr + i * 16 + quad * 4 + r) * 136 + wc + j * 16 + l16] =
            __float2bfloat16(acc[i][j][r] + pre[i][r]);
  __syncthreads();
  int mr = tid >> 2, seg = tid & 3;  // 4 threads/row, 32 elems each
  const __hip_bfloat16* rowp = &epi[mr * 136 + seg * 32];
  size_t obase = cbase + (size_t)(m0 + mr) * 4096 + n0 + seg * 32;
#pragma unroll
  for (int c = 0; c < 4; c++) {
    bf16x8 val = *(const bf16x8*)(rowp + c * 8);
    size_t idx = obase + c * 8;
    float4 r0 = *(const float4*)&resid[idx];
    float4 r1 = *(const float4*)&resid[idx + 4];
    float4 o0, o1;
    o0.x = r0.x + (float)val[0]; o0.y = r0.y + (float)val[1];
    o0.z = r0.z + (float)val[2]; o0.w = r0.w + (float)val[3];
    o1.x = r1.x + (float)val[4]; o1.y = r1.y + (float)val[5];
    o1.z = r1.z + (float)val[6]; o1.w = r1.w + (float)val[7];
    *(float4*)&out[idx] = o0;
    *(float4*)&out[idx + 4] = o1;
  }
}

extern "C" void kernel_launch(void* const* d_in, const int* in_sizes, int n_in,
                              void* d_out, int out_size, void* d_ws,
                              size_t ws_size, hipStream_t stream) {
  const float* xp  = (const float*)d_in[0];
  const float* gwp = (const float*)d_in[1];
  const float* gbp = (const float*)d_in[2];
  const float* wqp = (const float*)d_in[3];
  const float* bqp = (const float*)d_in[4];
  const float* wkp = (const float*)d_in[5];
  const float* bkp = (const float*)d_in[6];
  const float* wvp = (const float*)d_in[7];
  const float* bvp = (const float*)d_in[8];
  const float* wop = (const float*)d_in[9];
  const float* bop = (const float*)d_in[10];
  float* outp = (float*)d_out;

  char* w = (char*)d_ws;
  size_t off = 0;
  auto alloc = [&](size_t bytes) {
    void* p = w + off;
    off += (bytes + 255) & ~(size_t)255;
    return p;
  };
  float* stats         = (float*)alloc(64 * 2 * sizeof(float));
  __hip_bfloat16* hf   = (__hip_bfloat16*)alloc((size_t)2 * 4096 * 512 * 2);
  __hip_bfloat16* wqkb = (__hip_bfloat16*)alloc((size_t)1024 * 512 * 2);
  __hip_bfloat16* wvb  = (__hip_bfloat16*)alloc((size_t)512 * 512 * 2);
  __hip_bfloat16* wob  = (__hip_bfloat16*)alloc((size_t)512 * 512 * 2);
  float* bqk           = (float*)alloc(1024 * sizeof(float));
  float* psums         = (float*)alloc((size_t)32 * 8192 * sizeof(float));
  __hip_bfloat16* qk   = (__hip_bfloat16*)alloc((size_t)2 * 4096 * 1024 * 2);
  __hip_bfloat16* vT   = (__hip_bfloat16*)alloc((size_t)2 * 512 * 4096 * 2);
  __hip_bfloat16* obuf = (__hip_bfloat16*)alloc((size_t)2 * 4096 * 512 * 2);
  __hip_bfloat16* Sbuf = (__hip_bfloat16*)alloc((size_t)2 * 4096 * 4096 * 2);

  // prelude: 4096 cvt blocks + 64 gn_stats blocks + 1 bcat block
  prelude_k<<<4161, 256, 0, stream>>>(wqp, wkp, wvp, wop, wqkb, wvb, wob,
                                      bqp, bkp, bqk, xp, stats);

  gn_apply_k<<<dim3(8, 64, 2), 256, 0, stream>>>(xp, stats, gwp, gbp, hf);

  // fused QKV: qk[8192][1024] and vT[2][512][4096]
  qkv_k<<<dim3(12, 64, 1), 256, 0, stream>>>(hf, wqkb, wvb, bqk, bvp, qk, vT);

  // expS = exp(Q K^T * scale), both batches (bf16) + per-n-tile row sums
  qkexp_k<<<dim3(32, 32, 2), 256, 0, stream>>>(qk, qk, Sbuf, psums);

  // PV full-K, normalized inline (psums complete) -> obuf directly
  pv_k<<<512, 256, 0, stream>>>(Sbuf, vT, psums, obuf);

  // out[b][c][t] = x + Wo*O + bo  (64x128 tiles, 512 blocks)
  oproj_k<<<dim3(32, 8, 2), 256, 0, stream>>>(wob, obuf, outp, bop, xp);
}